// Round 1
// baseline (2923.548 us; speedup 1.0000x reference)
//
#include <hip/hip_runtime.h>

#define NUM_CN   25000
#define NUM_VN   50000
#define NUM_E    200000
#define D_EMBED  16
#define D_HIDDEN 32
#define D_MSG    16
#define BATCH    16

// One thread per (edge, batch). Gathers the two endpoint embeddings,
// runs the 32->32(relu)->16 MLP with wave-uniform weight reads (scalar
// loads), applies the syndrome mask via early-exit, scatter-adds the
// 16-float message with atomics.
__global__ __launch_bounds__(256) void edge_msg_kernel(
    const float* __restrict__ h_from,   // [B, NUM_CN, 16]
    const float* __restrict__ h_to,     // [B, NUM_VN, 16]
    const int*   __restrict__ syn,      // [B, NUM_CN]
    const int*   __restrict__ from_ind, // [E]
    const int*   __restrict__ to_ind,   // [E]
    const float* __restrict__ W1,       // [32, 32] row-major
    const float* __restrict__ W2,       // [32, 16] row-major
    float*       __restrict__ m_out)    // [B, NUM_VN, 16] accumulators
{
    const int e = blockIdx.x * blockDim.x + threadIdx.x;
    const int b = blockIdx.y;
    if (e >= NUM_E) return;

    const int from = from_ind[e];
    const int to   = to_ind[e];
    // syndrome mask multiplies the whole message by 0 -> skip everything
    if (syn[b * NUM_CN + from] == 0) return;

    const float* pf = h_from + ((size_t)b * NUM_CN + from) * D_EMBED;
    const float* pt = h_to   + ((size_t)b * NUM_VN + to)   * D_EMBED;

    float f[2 * D_EMBED];
#pragma unroll
    for (int i = 0; i < 4; ++i) {
        float4 v = ((const float4*)pf)[i];
        f[4 * i + 0] = v.x; f[4 * i + 1] = v.y;
        f[4 * i + 2] = v.z; f[4 * i + 3] = v.w;
    }
#pragma unroll
    for (int i = 0; i < 4; ++i) {
        float4 v = ((const float4*)pt)[i];
        f[16 + 4 * i + 0] = v.x; f[16 + 4 * i + 1] = v.y;
        f[16 + 4 * i + 2] = v.z; f[16 + 4 * i + 3] = v.w;
    }

    float hid[D_HIDDEN];
#pragma unroll
    for (int j = 0; j < D_HIDDEN; ++j) hid[j] = 0.0f;
    // i outer, j inner: W1 row-contiguous, uniform addresses -> s_load
#pragma unroll
    for (int i = 0; i < 2 * D_EMBED; ++i) {
        const float fi = f[i];
#pragma unroll
        for (int j = 0; j < D_HIDDEN; ++j)
            hid[j] = fmaf(fi, W1[i * D_HIDDEN + j], hid[j]);
    }
#pragma unroll
    for (int j = 0; j < D_HIDDEN; ++j) hid[j] = fmaxf(hid[j], 0.0f);

    float msg[D_MSG];
#pragma unroll
    for (int k = 0; k < D_MSG; ++k) msg[k] = 0.0f;
#pragma unroll
    for (int j = 0; j < D_HIDDEN; ++j) {
        const float hj = hid[j];
#pragma unroll
        for (int k = 0; k < D_MSG; ++k)
            msg[k] = fmaf(hj, W2[j * D_MSG + k], msg[k]);
    }

    float* pm = m_out + ((size_t)b * NUM_VN + to) * D_MSG;
#pragma unroll
    for (int k = 0; k < D_MSG; ++k)
        atomicAdd(&pm[k], msg[k]);
}

// One thread per (node, batch): feat = [m_x | m_z | h_to] (48) ->
// 48->32(relu)->16. m_x aliases `out` (d_out), so those two pointers are
// deliberately NOT __restrict__ — each thread reads its own 16 floats
// before overwriting them.
__global__ __launch_bounds__(256) void node_kernel(
    const float*              m_x,      // [B, NUM_VN, 16]  (aliases out)
    const float* __restrict__ m_z,      // [B, NUM_VN, 16]
    const float* __restrict__ h_to,     // [B, NUM_VN, 16]
    const float* __restrict__ We1,      // [48, 32]
    const float* __restrict__ We2,      // [32, 16]
    float*                    out)      // [B, NUM_VN, 16]
{
    const int n = blockIdx.x * blockDim.x + threadIdx.x;
    const int b = blockIdx.y;
    if (n >= NUM_VN) return;

    const size_t base = ((size_t)b * NUM_VN + n) * 16;

    float f[48];
#pragma unroll
    for (int i = 0; i < 4; ++i) {
        float4 v = ((const float4*)(m_x + base))[i];
        f[4 * i + 0] = v.x; f[4 * i + 1] = v.y;
        f[4 * i + 2] = v.z; f[4 * i + 3] = v.w;
    }
#pragma unroll
    for (int i = 0; i < 4; ++i) {
        float4 v = ((const float4*)(m_z + base))[i];
        f[16 + 4 * i + 0] = v.x; f[16 + 4 * i + 1] = v.y;
        f[16 + 4 * i + 2] = v.z; f[16 + 4 * i + 3] = v.w;
    }
#pragma unroll
    for (int i = 0; i < 4; ++i) {
        float4 v = ((const float4*)(h_to + base))[i];
        f[32 + 4 * i + 0] = v.x; f[32 + 4 * i + 1] = v.y;
        f[32 + 4 * i + 2] = v.z; f[32 + 4 * i + 3] = v.w;
    }

    float hid[D_HIDDEN];
#pragma unroll
    for (int j = 0; j < D_HIDDEN; ++j) hid[j] = 0.0f;
#pragma unroll
    for (int i = 0; i < 48; ++i) {
        const float fi = f[i];
#pragma unroll
        for (int j = 0; j < D_HIDDEN; ++j)
            hid[j] = fmaf(fi, We1[i * D_HIDDEN + j], hid[j]);
    }
#pragma unroll
    for (int j = 0; j < D_HIDDEN; ++j) hid[j] = fmaxf(hid[j], 0.0f);

    float o[D_EMBED];
#pragma unroll
    for (int k = 0; k < D_EMBED; ++k) o[k] = 0.0f;
#pragma unroll
    for (int j = 0; j < D_HIDDEN; ++j) {
        const float hj = hid[j];
#pragma unroll
        for (int k = 0; k < D_EMBED; ++k)
            o[k] = fmaf(hj, We2[k + j * D_EMBED], o[k]);
    }

#pragma unroll
    for (int i = 0; i < 4; ++i) {
        float4 v;
        v.x = o[4 * i + 0]; v.y = o[4 * i + 1];
        v.z = o[4 * i + 2]; v.w = o[4 * i + 3];
        ((float4*)(out + base))[i] = v;
    }
}

extern "C" void kernel_launch(void* const* d_in, const int* in_sizes, int n_in,
                              void* d_out, int out_size, void* d_ws, size_t ws_size,
                              hipStream_t stream) {
    const float* h_from_x = (const float*)d_in[0];
    const float* h_from_z = (const float*)d_in[1];
    const float* h_to     = (const float*)d_in[2];
    const int*   syn_x    = (const int*)d_in[3];
    const int*   syn_z    = (const int*)d_in[4];
    const int*   fi_x     = (const int*)d_in[5];
    const int*   ti_x     = (const int*)d_in[6];
    const int*   fi_z     = (const int*)d_in[7];
    const int*   ti_z     = (const int*)d_in[8];
    const float* Wx1      = (const float*)d_in[9];
    const float* Wx2      = (const float*)d_in[10];
    const float* Wz1      = (const float*)d_in[11];
    const float* Wz2      = (const float*)d_in[12];
    const float* We1      = (const float*)d_in[13];
    const float* We2      = (const float*)d_in[14];

    float* out = (float*)d_out;              // m_x accumulator, then final out
    float* m_z = (float*)d_ws;               // m_z accumulator (51.2 MB)

    const size_t m_bytes = (size_t)BATCH * NUM_VN * D_MSG * sizeof(float);

    // zero the accumulators (harness poisons d_out / d_ws with 0xAA)
    hipMemsetAsync(out, 0, m_bytes, stream);
    hipMemsetAsync(m_z, 0, m_bytes, stream);

    dim3 blk(256);
    dim3 grid_e((NUM_E + 255) / 256, BATCH);
    edge_msg_kernel<<<grid_e, blk, 0, stream>>>(h_from_x, h_to, syn_x, fi_x, ti_x,
                                                Wx1, Wx2, out);
    edge_msg_kernel<<<grid_e, blk, 0, stream>>>(h_from_z, h_to, syn_z, fi_z, ti_z,
                                                Wz1, Wz2, m_z);

    dim3 grid_n((NUM_VN + 255) / 256, BATCH);
    node_kernel<<<grid_n, blk, 0, stream>>>(out, m_z, h_to, We1, We2, out);
}

// Round 2
// 577.505 us; speedup vs baseline: 5.0624x; 5.0624x over previous
//
#include <hip/hip_runtime.h>

#define NUM_CN   25000
#define NUM_VN   50000
#define NUM_E    200000
#define D_EMBED  16
#define D_HIDDEN 32
#define D_MSG    16
#define BATCH    16

// ---------------------------------------------------------------------------
// CSR build: histogram -> two-level scan -> fill.
// Workspace layout (ints), ~3.2 MB total:
#define WS_IDS_X   0
#define WS_IDS_Z   200000
#define WS_OFF_X   400000      // 50001
#define WS_OFF_Z   450001      // 50001
#define WS_CNT_X   500002      // 50000
#define WS_CNT_Z   550002      // 50000
#define WS_CUR_X   600002      // 50000
#define WS_CUR_Z   650002      // 50000
#define WS_INCL_X  700002      // 51200 (50 chunks x 1024)
#define WS_INCL_Z  751202      // 51200
#define WS_PSUM    802402      // [2][64] per-chunk totals
#define WS_BASE    802530      // [2][64] exclusive chunk bases
#define SCAN_CHUNKS 49          // ceil(50000/1024)

__global__ __launch_bounds__(256) void hist_kernel(
    const int* __restrict__ ti_x, const int* __restrict__ ti_z,
    int* __restrict__ cnt_x, int* __restrict__ cnt_z)
{
    int e = blockIdx.x * 256 + threadIdx.x;
    if (e >= NUM_E) return;
    atomicAdd(&cnt_x[ti_x[e]], 1);
    atomicAdd(&cnt_z[ti_z[e]], 1);
}

// S1: per-chunk inclusive scan (1024 elems / block), chunk totals to psum.
__global__ __launch_bounds__(1024) void scan1_kernel(
    const int* __restrict__ cnt_x, const int* __restrict__ cnt_z,
    int* __restrict__ incl_x, int* __restrict__ incl_z,
    int* __restrict__ psum)
{
    __shared__ int s[1024];
    const int ch  = blockIdx.y;
    const int blk = blockIdx.x;
    const int t   = threadIdx.x;
    const int gid = blk * 1024 + t;
    const int* cnt  = ch ? cnt_z  : cnt_x;
    int*       incl = ch ? incl_z : incl_x;
    int v = (gid < NUM_VN) ? cnt[gid] : 0;
    s[t] = v;
    __syncthreads();
#pragma unroll
    for (int d = 1; d < 1024; d <<= 1) {
        int x = 0;
        if (t >= d) x = s[t - d];
        __syncthreads();
        if (t >= d) s[t] += x;
        __syncthreads();
    }
    incl[gid] = s[t];
    if (t == 1023) psum[ch * 64 + blk] = s[1023];
}

// S2: exclusive scan of the <=49 chunk totals (one thread per channel).
__global__ void scan2_kernel(const int* __restrict__ psum, int* __restrict__ base)
{
    int ch = threadIdx.x;
    if (ch >= 2) return;
    int run = 0;
    for (int i = 0; i < SCAN_CHUNKS; ++i) {
        base[ch * 64 + i] = run;
        run += psum[ch * 64 + i];
    }
}

// S3: produce off[] (exclusive, with off[0]=0 .. off[NUM_VN]=E) and cur[]=off[i].
__global__ __launch_bounds__(1024) void scan3_kernel(
    const int* __restrict__ cnt_x, const int* __restrict__ cnt_z,
    const int* __restrict__ incl_x, const int* __restrict__ incl_z,
    const int* __restrict__ base,
    int* __restrict__ off_x, int* __restrict__ off_z,
    int* __restrict__ cur_x, int* __restrict__ cur_z)
{
    const int ch  = blockIdx.y;
    const int blk = blockIdx.x;
    const int t   = threadIdx.x;
    const int i   = blk * 1024 + t;
    if (i >= NUM_VN) return;
    const int* cnt  = ch ? cnt_z  : cnt_x;
    const int* incl = ch ? incl_z : incl_x;
    int*       off  = ch ? off_z  : off_x;
    int*       cur  = ch ? cur_z  : cur_x;
    int bs = base[ch * 64 + blk];
    int iv = incl[i];
    off[i + 1] = bs + iv;
    cur[i]     = bs + iv - cnt[i];
    if (i == 0) off[0] = 0;
}

__global__ __launch_bounds__(256) void fill_kernel(
    const int* __restrict__ ti_x, const int* __restrict__ ti_z,
    int* __restrict__ cur_x, int* __restrict__ cur_z,
    int* __restrict__ ids_x, int* __restrict__ ids_z)
{
    int e = blockIdx.x * 256 + threadIdx.x;
    if (e >= NUM_E) return;
    int px = atomicAdd(&cur_x[ti_x[e]], 1);
    ids_x[px] = e;
    int pz = atomicAdd(&cur_z[ti_z[e]], 1);
    ids_z[pz] = e;
}

// ---------------------------------------------------------------------------
// Fused gather: thread = (node n, batch b), b = lane&15 so each 16-lane group
// shares n (identical edge trip counts -> minimal divergence). Accumulates
// m_x, m_z in registers, then applies the node MLP and writes final output.
// The h_to half of W1 is hoisted out of the edge loop (relu comes after sum).
__global__ __launch_bounds__(256) void fused_gather_kernel(
    const float* __restrict__ h_from_x, const float* __restrict__ h_from_z,
    const float* __restrict__ h_to,
    const int* __restrict__ syn_x, const int* __restrict__ syn_z,
    const int* __restrict__ from_ind_x, const int* __restrict__ from_ind_z,
    const int* __restrict__ off_x, const int* __restrict__ ids_x,
    const int* __restrict__ off_z, const int* __restrict__ ids_z,
    const float* __restrict__ Wx1, const float* __restrict__ Wx2,
    const float* __restrict__ Wz1, const float* __restrict__ Wz2,
    const float* __restrict__ We1, const float* __restrict__ We2,
    float* __restrict__ out)
{
    const int t = blockIdx.x * 256 + threadIdx.x;
    if (t >= NUM_VN * BATCH) return;
    const int b = t & (BATCH - 1);
    const int n = t >> 4;

    const size_t base_to = ((size_t)b * NUM_VN + n) * D_EMBED;

    float ht[D_EMBED];
#pragma unroll
    for (int i = 0; i < 4; ++i) {
        float4 v = ((const float4*)(h_to + base_to))[i];
        ht[4 * i + 0] = v.x; ht[4 * i + 1] = v.y;
        ht[4 * i + 2] = v.z; ht[4 * i + 3] = v.w;
    }

    float mx[D_MSG];
    float mz[D_MSG];
#pragma unroll
    for (int k = 0; k < D_MSG; ++k) { mx[k] = 0.0f; mz[k] = 0.0f; }

    // ---------------- channel X ----------------
    {
        float hid0[D_HIDDEN];
#pragma unroll
        for (int j = 0; j < D_HIDDEN; ++j) hid0[j] = 0.0f;
#pragma unroll
        for (int i = 0; i < D_EMBED; ++i) {
            const float hi = ht[i];
#pragma unroll
            for (int j = 0; j < D_HIDDEN; ++j)
                hid0[j] = fmaf(hi, Wx1[(D_EMBED + i) * D_HIDDEN + j], hid0[j]);
        }
        const int ks = off_x[n], ke = off_x[n + 1];
        for (int k = ks; k < ke; ++k) {
            const int e    = ids_x[k];
            const int from = from_ind_x[e];
            if (syn_x[b * NUM_CN + from] == 0) continue;
            const float* pf = h_from_x + ((size_t)b * NUM_CN + from) * D_EMBED;
            float hf[D_EMBED];
#pragma unroll
            for (int i = 0; i < 4; ++i) {
                float4 v = ((const float4*)pf)[i];
                hf[4 * i + 0] = v.x; hf[4 * i + 1] = v.y;
                hf[4 * i + 2] = v.z; hf[4 * i + 3] = v.w;
            }
            float hid[D_HIDDEN];
#pragma unroll
            for (int j = 0; j < D_HIDDEN; ++j) hid[j] = hid0[j];
#pragma unroll
            for (int i = 0; i < D_EMBED; ++i) {
                const float fi = hf[i];
#pragma unroll
                for (int j = 0; j < D_HIDDEN; ++j)
                    hid[j] = fmaf(fi, Wx1[i * D_HIDDEN + j], hid[j]);
            }
#pragma unroll
            for (int j = 0; j < D_HIDDEN; ++j) hid[j] = fmaxf(hid[j], 0.0f);
#pragma unroll
            for (int j = 0; j < D_HIDDEN; ++j) {
                const float hj = hid[j];
#pragma unroll
                for (int k2 = 0; k2 < D_MSG; ++k2)
                    mx[k2] = fmaf(hj, Wx2[j * D_MSG + k2], mx[k2]);
            }
        }
    }

    // ---------------- channel Z ----------------
    {
        float hid0[D_HIDDEN];
#pragma unroll
        for (int j = 0; j < D_HIDDEN; ++j) hid0[j] = 0.0f;
#pragma unroll
        for (int i = 0; i < D_EMBED; ++i) {
            const float hi = ht[i];
#pragma unroll
            for (int j = 0; j < D_HIDDEN; ++j)
                hid0[j] = fmaf(hi, Wz1[(D_EMBED + i) * D_HIDDEN + j], hid0[j]);
        }
        const int ks = off_z[n], ke = off_z[n + 1];
        for (int k = ks; k < ke; ++k) {
            const int e    = ids_z[k];
            const int from = from_ind_z[e];
            if (syn_z[b * NUM_CN + from] == 0) continue;
            const float* pf = h_from_z + ((size_t)b * NUM_CN + from) * D_EMBED;
            float hf[D_EMBED];
#pragma unroll
            for (int i = 0; i < 4; ++i) {
                float4 v = ((const float4*)pf)[i];
                hf[4 * i + 0] = v.x; hf[4 * i + 1] = v.y;
                hf[4 * i + 2] = v.z; hf[4 * i + 3] = v.w;
            }
            float hid[D_HIDDEN];
#pragma unroll
            for (int j = 0; j < D_HIDDEN; ++j) hid[j] = hid0[j];
#pragma unroll
            for (int i = 0; i < D_EMBED; ++i) {
                const float fi = hf[i];
#pragma unroll
                for (int j = 0; j < D_HIDDEN; ++j)
                    hid[j] = fmaf(fi, Wz1[i * D_HIDDEN + j], hid[j]);
            }
#pragma unroll
            for (int j = 0; j < D_HIDDEN; ++j) hid[j] = fmaxf(hid[j], 0.0f);
#pragma unroll
            for (int j = 0; j < D_HIDDEN; ++j) {
                const float hj = hid[j];
#pragma unroll
                for (int k2 = 0; k2 < D_MSG; ++k2)
                    mz[k2] = fmaf(hj, Wz2[j * D_MSG + k2], mz[k2]);
            }
        }
    }

    // ---------------- node MLP: [mx | mz | ht](48) -> 32 relu -> 16 -------
    float hid[D_HIDDEN];
#pragma unroll
    for (int j = 0; j < D_HIDDEN; ++j) hid[j] = 0.0f;
#pragma unroll
    for (int i = 0; i < D_MSG; ++i) {
        const float fi = mx[i];
#pragma unroll
        for (int j = 0; j < D_HIDDEN; ++j)
            hid[j] = fmaf(fi, We1[i * D_HIDDEN + j], hid[j]);
    }
#pragma unroll
    for (int i = 0; i < D_MSG; ++i) {
        const float fi = mz[i];
#pragma unroll
        for (int j = 0; j < D_HIDDEN; ++j)
            hid[j] = fmaf(fi, We1[(D_MSG + i) * D_HIDDEN + j], hid[j]);
    }
#pragma unroll
    for (int i = 0; i < D_EMBED; ++i) {
        const float fi = ht[i];
#pragma unroll
        for (int j = 0; j < D_HIDDEN; ++j)
            hid[j] = fmaf(fi, We1[(2 * D_MSG + i) * D_HIDDEN + j], hid[j]);
    }
#pragma unroll
    for (int j = 0; j < D_HIDDEN; ++j) hid[j] = fmaxf(hid[j], 0.0f);

    float o[D_EMBED];
#pragma unroll
    for (int k = 0; k < D_EMBED; ++k) o[k] = 0.0f;
#pragma unroll
    for (int j = 0; j < D_HIDDEN; ++j) {
        const float hj = hid[j];
#pragma unroll
        for (int k = 0; k < D_EMBED; ++k)
            o[k] = fmaf(hj, We2[j * D_EMBED + k], o[k]);
    }

#pragma unroll
    for (int i = 0; i < 4; ++i) {
        float4 v;
        v.x = o[4 * i + 0]; v.y = o[4 * i + 1];
        v.z = o[4 * i + 2]; v.w = o[4 * i + 3];
        ((float4*)(out + base_to))[i] = v;
    }
}

// ---------------------------------------------------------------------------
extern "C" void kernel_launch(void* const* d_in, const int* in_sizes, int n_in,
                              void* d_out, int out_size, void* d_ws, size_t ws_size,
                              hipStream_t stream) {
    const float* h_from_x = (const float*)d_in[0];
    const float* h_from_z = (const float*)d_in[1];
    const float* h_to     = (const float*)d_in[2];
    const int*   syn_x    = (const int*)d_in[3];
    const int*   syn_z    = (const int*)d_in[4];
    const int*   fi_x     = (const int*)d_in[5];
    const int*   ti_x     = (const int*)d_in[6];
    const int*   fi_z     = (const int*)d_in[7];
    const int*   ti_z     = (const int*)d_in[8];
    const float* Wx1      = (const float*)d_in[9];
    const float* Wx2      = (const float*)d_in[10];
    const float* Wz1      = (const float*)d_in[11];
    const float* Wz2      = (const float*)d_in[12];
    const float* We1      = (const float*)d_in[13];
    const float* We2      = (const float*)d_in[14];

    int* ws = (int*)d_ws;
    int* ids_x  = ws + WS_IDS_X;
    int* ids_z  = ws + WS_IDS_Z;
    int* off_x  = ws + WS_OFF_X;
    int* off_z  = ws + WS_OFF_Z;
    int* cnt_x  = ws + WS_CNT_X;
    int* cnt_z  = ws + WS_CNT_Z;
    int* cur_x  = ws + WS_CUR_X;
    int* cur_z  = ws + WS_CUR_Z;
    int* incl_x = ws + WS_INCL_X;
    int* incl_z = ws + WS_INCL_Z;
    int* psum   = ws + WS_PSUM;
    int* base   = ws + WS_BASE;

    // zero the two count arrays (contiguous: cnt_x then cnt_z)
    hipMemsetAsync(cnt_x, 0, 2 * NUM_VN * sizeof(int), stream);

    hist_kernel<<<dim3((NUM_E + 255) / 256), dim3(256), 0, stream>>>(
        ti_x, ti_z, cnt_x, cnt_z);
    scan1_kernel<<<dim3(SCAN_CHUNKS, 2), dim3(1024), 0, stream>>>(
        cnt_x, cnt_z, incl_x, incl_z, psum);
    scan2_kernel<<<dim3(1), dim3(64), 0, stream>>>(psum, base);
    scan3_kernel<<<dim3(SCAN_CHUNKS, 2), dim3(1024), 0, stream>>>(
        cnt_x, cnt_z, incl_x, incl_z, base, off_x, off_z, cur_x, cur_z);
    fill_kernel<<<dim3((NUM_E + 255) / 256), dim3(256), 0, stream>>>(
        ti_x, ti_z, cur_x, cur_z, ids_x, ids_z);

    fused_gather_kernel<<<dim3((NUM_VN * BATCH) / 256), dim3(256), 0, stream>>>(
        h_from_x, h_from_z, h_to, syn_x, syn_z, fi_x, fi_z,
        off_x, ids_x, off_z, ids_z,
        Wx1, Wx2, Wz1, Wz2, We1, We2, (float*)d_out);
}

// Round 3
// 525.208 us; speedup vs baseline: 5.5665x; 1.0996x over previous
//
#include <hip/hip_runtime.h>

#define NUM_CN   25000
#define NUM_VN   50000
#define NUM_E    200000
#define D_EMBED  16
#define D_HIDDEN 32
#define D_MSG    16
#define BATCH    16

// ---------------------------------------------------------------------------
// Workspace layout (int units):
#define WS_IDS_X   0           // 200000   (stores FROM node ids, CSR order)
#define WS_IDS_Z   200000      // 200000
#define WS_OFF_X   400000      // 50001
#define WS_OFF_Z   450001      // 50001
#define WS_CNT_X   500002      // 50000
#define WS_CNT_Z   550002      // 50000
#define WS_CUR_X   600002      // 50000
#define WS_CUR_Z   650002      // 50000
#define WS_INCL_X  700002      // 51200
#define WS_INCL_Z  751202      // 51200
#define WS_PSUM    802402      // 128
#define WS_BASE    802530      // 128
#define WS_A1X     802816      // 6400000 ints = 25.6 MB bf16 (aligned: byte%16==0)
#define WS_A1Z     7202816     // 6400000
#define WS_END_A1  13602816    // total 54.41 MB if A1 path used
#define SCAN_CHUNKS 49

__global__ __launch_bounds__(256) void hist_kernel(
    const int* __restrict__ ti_x, const int* __restrict__ ti_z,
    int* __restrict__ cnt_x, int* __restrict__ cnt_z)
{
    int e = blockIdx.x * 256 + threadIdx.x;
    if (e >= NUM_E) return;
    atomicAdd(&cnt_x[ti_x[e]], 1);
    atomicAdd(&cnt_z[ti_z[e]], 1);
}

__global__ __launch_bounds__(1024) void scan1_kernel(
    const int* __restrict__ cnt_x, const int* __restrict__ cnt_z,
    int* __restrict__ incl_x, int* __restrict__ incl_z,
    int* __restrict__ psum)
{
    __shared__ int s[1024];
    const int ch  = blockIdx.y;
    const int blk = blockIdx.x;
    const int t   = threadIdx.x;
    const int gid = blk * 1024 + t;
    const int* cnt  = ch ? cnt_z  : cnt_x;
    int*       incl = ch ? incl_z : incl_x;
    int v = (gid < NUM_VN) ? cnt[gid] : 0;
    s[t] = v;
    __syncthreads();
#pragma unroll
    for (int d = 1; d < 1024; d <<= 1) {
        int x = 0;
        if (t >= d) x = s[t - d];
        __syncthreads();
        if (t >= d) s[t] += x;
        __syncthreads();
    }
    incl[gid] = s[t];
    if (t == 1023) psum[ch * 64 + blk] = s[1023];
}

__global__ void scan2_kernel(const int* __restrict__ psum, int* __restrict__ base)
{
    int ch = threadIdx.x;
    if (ch >= 2) return;
    int run = 0;
    for (int i = 0; i < SCAN_CHUNKS; ++i) {
        base[ch * 64 + i] = run;
        run += psum[ch * 64 + i];
    }
}

__global__ __launch_bounds__(1024) void scan3_kernel(
    const int* __restrict__ cnt_x, const int* __restrict__ cnt_z,
    const int* __restrict__ incl_x, const int* __restrict__ incl_z,
    const int* __restrict__ base,
    int* __restrict__ off_x, int* __restrict__ off_z,
    int* __restrict__ cur_x, int* __restrict__ cur_z)
{
    const int ch  = blockIdx.y;
    const int blk = blockIdx.x;
    const int t   = threadIdx.x;
    const int i   = blk * 1024 + t;
    if (i >= NUM_VN) return;
    const int* cnt  = ch ? cnt_z  : cnt_x;
    const int* incl = ch ? incl_z : incl_x;
    int*       off  = ch ? off_z  : off_x;
    int*       cur  = ch ? cur_z  : cur_x;
    int bs = base[ch * 64 + blk];
    int iv = incl[i];
    off[i + 1] = bs + iv;
    cur[i]     = bs + iv - cnt[i];
    if (i == 0) off[0] = 0;
}

// fill: CSR slot stores the FROM node id directly (removes one indirection).
__global__ __launch_bounds__(256) void fill_kernel(
    const int* __restrict__ ti_x, const int* __restrict__ ti_z,
    const int* __restrict__ fi_x, const int* __restrict__ fi_z,
    int* __restrict__ cur_x, int* __restrict__ cur_z,
    int* __restrict__ ids_x, int* __restrict__ ids_z)
{
    int e = blockIdx.x * 256 + threadIdx.x;
    if (e >= NUM_E) return;
    int px = atomicAdd(&cur_x[ti_x[e]], 1);
    ids_x[px] = fi_x[e];
    int pz = atomicAdd(&cur_z[ti_z[e]], 1);
    ids_z[pz] = fi_z[e];
}

// ---------------------------------------------------------------------------
// a1[ch][cn][b][32] = h_from[b,cn,:] @ W1[0:16,:]   stored bf16, lane-interleaved:
// per-cn block of 64 uint4; lane b's p-th uint4 at block + p*16 + b so the 16
// batch-lanes of a node-group load contiguous 256 B per instruction.
__device__ __forceinline__ unsigned pack_bf16(float a, float b) {
    unsigned ua = __float_as_uint(a); ua += 0x7fff + ((ua >> 16) & 1);
    unsigned ub = __float_as_uint(b); ub += 0x7fff + ((ub >> 16) & 1);
    return (ua >> 16) | (ub & 0xffff0000u);
}

__global__ __launch_bounds__(256) void a1_kernel(
    const float* __restrict__ h_from_x, const float* __restrict__ h_from_z,
    const float* __restrict__ Wx1, const float* __restrict__ Wz1,
    uint4* __restrict__ a1x, uint4* __restrict__ a1z)
{
    int t = blockIdx.x * 256 + threadIdx.x;
    if (t >= NUM_CN * BATCH) return;
    const int ch = blockIdx.y;
    const int b  = t & 15;
    const int cn = t >> 4;
    const float* hsrc = (ch ? h_from_z : h_from_x) + ((size_t)b * NUM_CN + cn) * D_EMBED;
    const float* W1   = ch ? Wz1 : Wx1;
    uint4* dst = (ch ? a1z : a1x) + (size_t)cn * 64;

    float hf[D_EMBED];
#pragma unroll
    for (int i = 0; i < 4; ++i) {
        float4 v = ((const float4*)hsrc)[i];
        hf[4 * i + 0] = v.x; hf[4 * i + 1] = v.y;
        hf[4 * i + 2] = v.z; hf[4 * i + 3] = v.w;
    }
    float a[D_HIDDEN];
#pragma unroll
    for (int j = 0; j < D_HIDDEN; ++j) a[j] = 0.0f;
#pragma unroll
    for (int i = 0; i < D_EMBED; ++i) {
        const float fi = hf[i];
#pragma unroll
        for (int j = 0; j < D_HIDDEN; ++j)
            a[j] = fmaf(fi, W1[i * D_HIDDEN + j], a[j]);
    }
    unsigned u[16];
#pragma unroll
    for (int j = 0; j < 16; ++j) u[j] = pack_bf16(a[2 * j], a[2 * j + 1]);
#pragma unroll
    for (int p = 0; p < 4; ++p) {
        uint4 q;
        q.x = u[4 * p + 0]; q.y = u[4 * p + 1];
        q.z = u[4 * p + 2]; q.w = u[4 * p + 3];
        dst[p * 16 + b] = q;
    }
}

// ---------------------------------------------------------------------------
// Per-channel accumulation: hacc[32] = sum over incoming edges of
// syn * relu(a1[from] + a2), with a2 = h_to @ W1[16:32] computed once.
template <int USE_A1>
__device__ __forceinline__ void accum_channel(
    const float ht[D_EMBED], int n, int b,
    const int* __restrict__ off, const int* __restrict__ ids,
    const int* __restrict__ syn_b,
    const uint4* __restrict__ a1,
    const float* __restrict__ h_from,
    const float* __restrict__ W1,
    float hacc[D_HIDDEN])
{
    float hid0[D_HIDDEN];
#pragma unroll
    for (int j = 0; j < D_HIDDEN; ++j) hid0[j] = 0.0f;
#pragma unroll
    for (int i = 0; i < D_EMBED; ++i) {
        const float hi = ht[i];
#pragma unroll
        for (int j = 0; j < D_HIDDEN; ++j)
            hid0[j] = fmaf(hi, W1[(D_EMBED + i) * D_HIDDEN + j], hid0[j]);
    }
#pragma unroll
    for (int j = 0; j < D_HIDDEN; ++j) hacc[j] = 0.0f;

    const int ks = off[n], ke = off[n + 1];
    int from_n = 0, syn_n = 0;
    if (ks < ke) { from_n = ids[ks]; syn_n = syn_b[from_n]; }
    for (int k = ks; k < ke; ++k) {
        const int from = from_n;
        const int sy   = syn_n;
        if (k + 1 < ke) { from_n = ids[k + 1]; syn_n = syn_b[from_n]; }
        if (sy) {
            if (USE_A1) {
                const uint4* pa = a1 + (size_t)from * 64 + b;
                uint4 q0 = pa[0], q1 = pa[16], q2 = pa[32], q3 = pa[48];
                unsigned uu[16] = {q0.x, q0.y, q0.z, q0.w,
                                   q1.x, q1.y, q1.z, q1.w,
                                   q2.x, q2.y, q2.z, q2.w,
                                   q3.x, q3.y, q3.z, q3.w};
#pragma unroll
                for (int p = 0; p < 16; ++p) {
                    float lo = __uint_as_float(uu[p] << 16);
                    float hi = __uint_as_float(uu[p] & 0xffff0000u);
                    hacc[2 * p]     += fmaxf(hid0[2 * p] + lo, 0.0f);
                    hacc[2 * p + 1] += fmaxf(hid0[2 * p + 1] + hi, 0.0f);
                }
            } else {
                const float* pf = h_from + ((size_t)b * NUM_CN + from) * D_EMBED;
                float hf[D_EMBED];
#pragma unroll
                for (int i = 0; i < 4; ++i) {
                    float4 v = ((const float4*)pf)[i];
                    hf[4 * i + 0] = v.x; hf[4 * i + 1] = v.y;
                    hf[4 * i + 2] = v.z; hf[4 * i + 3] = v.w;
                }
                float hid[D_HIDDEN];
#pragma unroll
                for (int j = 0; j < D_HIDDEN; ++j) hid[j] = hid0[j];
#pragma unroll
                for (int i = 0; i < D_EMBED; ++i) {
                    const float fi = hf[i];
#pragma unroll
                    for (int j = 0; j < D_HIDDEN; ++j)
                        hid[j] = fmaf(fi, W1[i * D_HIDDEN + j], hid[j]);
                }
#pragma unroll
                for (int j = 0; j < D_HIDDEN; ++j)
                    hacc[j] += fmaxf(hid[j], 0.0f);
            }
        }
    }
}

template <int USE_A1>
__global__ __launch_bounds__(256) void fused_gather_kernel(
    const float* __restrict__ h_from_x, const float* __restrict__ h_from_z,
    const float* __restrict__ h_to,
    const int* __restrict__ syn_x, const int* __restrict__ syn_z,
    const int* __restrict__ off_x, const int* __restrict__ ids_x,
    const int* __restrict__ off_z, const int* __restrict__ ids_z,
    const uint4* __restrict__ a1x, const uint4* __restrict__ a1z,
    const float* __restrict__ Wx1, const float* __restrict__ Wx2,
    const float* __restrict__ Wz1, const float* __restrict__ Wz2,
    const float* __restrict__ We1, const float* __restrict__ We2,
    float* __restrict__ out)
{
    const int t = blockIdx.x * 256 + threadIdx.x;
    if (t >= NUM_VN * BATCH) return;
    const int b = t & (BATCH - 1);
    const int n = t >> 4;

    const size_t base_to = ((size_t)b * NUM_VN + n) * D_EMBED;

    float ht[D_EMBED];
#pragma unroll
    for (int i = 0; i < 4; ++i) {
        float4 v = ((const float4*)(h_to + base_to))[i];
        ht[4 * i + 0] = v.x; ht[4 * i + 1] = v.y;
        ht[4 * i + 2] = v.z; ht[4 * i + 3] = v.w;
    }

    float hacc[D_HIDDEN];
    float mx[D_MSG], mz[D_MSG];

    // X channel
    accum_channel<USE_A1>(ht, n, b, off_x, ids_x, syn_x + b * NUM_CN,
                          a1x, h_from_x, Wx1, hacc);
#pragma unroll
    for (int k = 0; k < D_MSG; ++k) mx[k] = 0.0f;
#pragma unroll
    for (int j = 0; j < D_HIDDEN; ++j) {
        const float hj = hacc[j];
#pragma unroll
        for (int k = 0; k < D_MSG; ++k)
            mx[k] = fmaf(hj, Wx2[j * D_MSG + k], mx[k]);
    }

    // Z channel
    accum_channel<USE_A1>(ht, n, b, off_z, ids_z, syn_z + b * NUM_CN,
                          a1z, h_from_z, Wz1, hacc);
#pragma unroll
    for (int k = 0; k < D_MSG; ++k) mz[k] = 0.0f;
#pragma unroll
    for (int j = 0; j < D_HIDDEN; ++j) {
        const float hj = hacc[j];
#pragma unroll
        for (int k = 0; k < D_MSG; ++k)
            mz[k] = fmaf(hj, Wz2[j * D_MSG + k], mz[k]);
    }

    // node MLP: [mx | mz | ht](48) -> 32 relu -> 16
    float hid[D_HIDDEN];
#pragma unroll
    for (int j = 0; j < D_HIDDEN; ++j) hid[j] = 0.0f;
#pragma unroll
    for (int i = 0; i < D_MSG; ++i) {
        const float fi = mx[i];
#pragma unroll
        for (int j = 0; j < D_HIDDEN; ++j)
            hid[j] = fmaf(fi, We1[i * D_HIDDEN + j], hid[j]);
    }
#pragma unroll
    for (int i = 0; i < D_MSG; ++i) {
        const float fi = mz[i];
#pragma unroll
        for (int j = 0; j < D_HIDDEN; ++j)
            hid[j] = fmaf(fi, We1[(D_MSG + i) * D_HIDDEN + j], hid[j]);
    }
#pragma unroll
    for (int i = 0; i < D_EMBED; ++i) {
        const float fi = ht[i];
#pragma unroll
        for (int j = 0; j < D_HIDDEN; ++j)
            hid[j] = fmaf(fi, We1[(2 * D_MSG + i) * D_HIDDEN + j], hid[j]);
    }
#pragma unroll
    for (int j = 0; j < D_HIDDEN; ++j) hid[j] = fmaxf(hid[j], 0.0f);

    float o[D_EMBED];
#pragma unroll
    for (int k = 0; k < D_EMBED; ++k) o[k] = 0.0f;
#pragma unroll
    for (int j = 0; j < D_HIDDEN; ++j) {
        const float hj = hid[j];
#pragma unroll
        for (int k = 0; k < D_EMBED; ++k)
            o[k] = fmaf(hj, We2[j * D_EMBED + k], o[k]);
    }

#pragma unroll
    for (int i = 0; i < 4; ++i) {
        float4 v;
        v.x = o[4 * i + 0]; v.y = o[4 * i + 1];
        v.z = o[4 * i + 2]; v.w = o[4 * i + 3];
        ((float4*)(out + base_to))[i] = v;
    }
}

// ---------------------------------------------------------------------------
extern "C" void kernel_launch(void* const* d_in, const int* in_sizes, int n_in,
                              void* d_out, int out_size, void* d_ws, size_t ws_size,
                              hipStream_t stream) {
    const float* h_from_x = (const float*)d_in[0];
    const float* h_from_z = (const float*)d_in[1];
    const float* h_to     = (const float*)d_in[2];
    const int*   syn_x    = (const int*)d_in[3];
    const int*   syn_z    = (const int*)d_in[4];
    const int*   fi_x     = (const int*)d_in[5];
    const int*   ti_x     = (const int*)d_in[6];
    const int*   fi_z     = (const int*)d_in[7];
    const int*   ti_z     = (const int*)d_in[8];
    const float* Wx1      = (const float*)d_in[9];
    const float* Wx2      = (const float*)d_in[10];
    const float* Wz1      = (const float*)d_in[11];
    const float* Wz2      = (const float*)d_in[12];
    const float* We1      = (const float*)d_in[13];
    const float* We2      = (const float*)d_in[14];

    int* ws = (int*)d_ws;
    int* ids_x  = ws + WS_IDS_X;
    int* ids_z  = ws + WS_IDS_Z;
    int* off_x  = ws + WS_OFF_X;
    int* off_z  = ws + WS_OFF_Z;
    int* cnt_x  = ws + WS_CNT_X;
    int* cnt_z  = ws + WS_CNT_Z;
    int* cur_x  = ws + WS_CUR_X;
    int* cur_z  = ws + WS_CUR_Z;
    int* incl_x = ws + WS_INCL_X;
    int* incl_z = ws + WS_INCL_Z;
    int* psum   = ws + WS_PSUM;
    int* base   = ws + WS_BASE;
    uint4* a1x  = (uint4*)(ws + WS_A1X);
    uint4* a1z  = (uint4*)(ws + WS_A1Z);

    const bool use_a1 = ws_size >= (size_t)WS_END_A1 * sizeof(int);

    hipMemsetAsync(cnt_x, 0, 2 * NUM_VN * sizeof(int), stream);

    hist_kernel<<<dim3((NUM_E + 255) / 256), dim3(256), 0, stream>>>(
        ti_x, ti_z, cnt_x, cnt_z);
    scan1_kernel<<<dim3(SCAN_CHUNKS, 2), dim3(1024), 0, stream>>>(
        cnt_x, cnt_z, incl_x, incl_z, psum);
    scan2_kernel<<<dim3(1), dim3(64), 0, stream>>>(psum, base);
    scan3_kernel<<<dim3(SCAN_CHUNKS, 2), dim3(1024), 0, stream>>>(
        cnt_x, cnt_z, incl_x, incl_z, base, off_x, off_z, cur_x, cur_z);
    fill_kernel<<<dim3((NUM_E + 255) / 256), dim3(256), 0, stream>>>(
        ti_x, ti_z, fi_x, fi_z, cur_x, cur_z, ids_x, ids_z);

    if (use_a1) {
        a1_kernel<<<dim3((NUM_CN * BATCH + 255) / 256, 2), dim3(256), 0, stream>>>(
            h_from_x, h_from_z, Wx1, Wz1, a1x, a1z);
        fused_gather_kernel<1><<<dim3((NUM_VN * BATCH) / 256), dim3(256), 0, stream>>>(
            h_from_x, h_from_z, h_to, syn_x, syn_z,
            off_x, ids_x, off_z, ids_z, a1x, a1z,
            Wx1, Wx2, Wz1, Wz2, We1, We2, (float*)d_out);
    } else {
        fused_gather_kernel<0><<<dim3((NUM_VN * BATCH) / 256), dim3(256), 0, stream>>>(
            h_from_x, h_from_z, h_to, syn_x, syn_z,
            off_x, ids_x, off_z, ids_z, a1x, a1z,
            Wx1, Wx2, Wz1, Wz2, We1, We2, (float*)d_out);
    }
}